// Round 1
// baseline (322.133 us; speedup 1.0000x reference)
//
#include <hip/hip_runtime.h>

#define DIM 1024
#define CHUNKS (DIM / 4)   // float4 chunks per row

// One Givens step: given (c,s), next input element vn and running carry
// (current value of column i), produce out[i] and the new carry (new value
// of column i+1). Both computed from the OLD carry.
__device__ __forceinline__ float rot_step(float2 cs, float vn, float& carry) {
    float o  = cs.x * carry - cs.y * vn;
    float nc = cs.y * carry + cs.x * vn;
    carry = nc;
    return o;
}

__global__ __launch_bounds__(256)
void qll_kernel(const float* __restrict__ x,
                const float* __restrict__ angles,
                float* __restrict__ out,
                int batch) {
    __shared__ float2 cs[DIM];
    // Build cos/sin table once per block (8 KB LDS). Cheap: 4 sincos/thread.
    for (int i = threadIdx.x; i < DIM; i += blockDim.x) {
        float a = angles[i];
        cs[i] = make_float2(cosf(a), sinf(a));
    }
    __syncthreads();

    int row = blockIdx.x * blockDim.x + threadIdx.x;
    if (row >= batch) return;

    const float4* __restrict__ vin = reinterpret_cast<const float4*>(x) + (size_t)row * CHUNKS;
    float4* __restrict__ vout      = reinterpret_cast<float4*>(out) + (size_t)row * CHUNKS;

    // Chunk 0: v[0..3]. carry starts as v[0]; steps 0,1,2 consume v[1..3].
    float4 v0 = vin[0];
    float carry = v0.x;
    float p0 = rot_step(cs[0], v0.y, carry);   // out[0] (provisional; fixed by step 1023)
    float p1 = rot_step(cs[1], v0.z, carry);   // out[1]
    float p2 = rot_step(cs[2], v0.w, carry);   // out[2]
    float out0_hold = p0;

    // Chunk 1 peeled: completes out[3]; first float4 held in regs until the
    // final rotation fixes out[0] (avoids a second store to the same address).
    float4 v1 = vin[1];
    float f3 = rot_step(cs[3], v1.x, carry);
    float4 first4 = make_float4(p0, p1, p2, f3);   // out[0..3], out[0] provisional
    p0 = rot_step(cs[4], v1.y, carry);
    p1 = rot_step(cs[5], v1.z, carry);
    p2 = rot_step(cs[6], v1.w, carry);

    // Steady state: chunk k consumes v[4k..4k+3] via steps 4k-1..4k+2,
    // completing output group k-1 = out[4k-4..4k-1].
#pragma unroll 4
    for (int k = 2; k < CHUNKS; ++k) {
        float4 vk = vin[k];
        int ib = 4 * k - 1;
        float o3 = rot_step(cs[ib], vk.x, carry);
        vout[k - 1] = make_float4(p0, p1, p2, o3);
        p0 = rot_step(cs[ib + 1], vk.y, carry);
        p1 = rot_step(cs[ib + 2], vk.z, carry);
        p2 = rot_step(cs[ib + 3], vk.w, carry);
    }

    // After the loop: p0,p1,p2 = out[1020..1022]; carry = current v[1023].
    // Step 1023 rotates (col 1023, col 0) where col 0 holds out0_hold.
    float2 csl = cs[DIM - 1];
    float o_last    = csl.x * carry - csl.y * out0_hold;
    float out0_final = csl.y * carry + csl.x * out0_hold;

    vout[CHUNKS - 1] = make_float4(p0, p1, p2, o_last);
    first4.x = out0_final;
    vout[0] = first4;
}

extern "C" void kernel_launch(void* const* d_in, const int* in_sizes, int n_in,
                              void* d_out, int out_size, void* d_ws, size_t ws_size,
                              hipStream_t stream) {
    const float* x      = (const float*)d_in[0];
    const float* angles = (const float*)d_in[1];
    float* out          = (float*)d_out;

    int batch = in_sizes[0] / DIM;   // 65536
    dim3 block(256);
    dim3 grid((batch + block.x - 1) / block.x);   // 256 blocks
    qll_kernel<<<grid, block, 0, stream>>>(x, angles, out, batch);
}

// Round 2
// 108.196 us; speedup vs baseline: 2.9773x; 2.9773x over previous
//
#include <hip/hip_runtime.h>

#define DIM   1024
#define LPR   32            // lanes cooperating on one row
#define SEG   (DIM / LPR)   // 32 floats per lane
#define SEG4  (SEG / 4)     // 8 float4 per lane
#define ROWS_PER_BLOCK 8    // 256 threads / 32
#define WAVES_PER_BLOCK 4

// Row recurrence (Givens sweep): carry = value of column i entering step i.
//   out[i]  = c_i*carry - s_i*v[i+1]
//   carry'  = s_i*carry + c_i*v[i+1]
// Affine in carry -> per-lane (A,B) + shfl scan parallelizes across 32 lanes.
__global__ __launch_bounds__(256)
void qll_kernel(const float* __restrict__ x,
                const float* __restrict__ angles,
                float* __restrict__ out,
                int batch)
{
    // cos/sin table, bank-transposed: step j stored at [(j&31)*32 + (j>>5)]
    // so the phase-loop read cs[i*32 + t] puts lane t in bank 2t%32 (2-way = free).
    __shared__ float2 cs[DIM];
    // wave-private output staging, +1 float4 pad per 8 to de-conflict reads
    __shared__ float4 stage[WAVES_PER_BLOCK][576];

    for (int j = threadIdx.x; j < DIM; j += blockDim.x) {
        float a = angles[j];
        int loc = (j & (LPR - 1)) * LPR + (j >> 5);
        cs[loc] = make_float2(cosf(a), sinf(a));
    }
    __syncthreads();

    const int tid  = threadIdx.x;
    const int grp  = tid >> 5;        // 32-lane group = one row (0..7)
    const int t    = tid & 31;        // segment index within row
    const int wave = tid >> 6;        // 0..3
    const int row  = blockIdx.x * ROWS_PER_BLOCK + grp;
    const bool active = row < batch;

    // ---- load this lane's 32-float segment into registers ----
    float v[SEG];
    const float4* vin4 = reinterpret_cast<const float4*>(x)
                       + (size_t)row * (DIM / 4) + t * SEG4;
    if (active) {
#pragma unroll
        for (int e = 0; e < SEG4; ++e) {
            float4 q = vin4[e];
            v[4*e+0] = q.x; v[4*e+1] = q.y; v[4*e+2] = q.z; v[4*e+3] = q.w;
        }
    } else {
#pragma unroll
        for (int e = 0; e < SEG; ++e) v[e] = 0.f;
    }

    // boundary exchanges (capture BEFORE phase 2 overwrites v[])
    float v0row = __shfl(v[0], 0, LPR);        // row's v[0]
    float v1row = __shfl(v[1], 0, LPR);        // row's v[1]
    float vnext = __shfl_down(v[0], 1, LPR);   // next lane's first elem (t=31: own, unused)

    // ---- phase 1: per-lane affine (A,B) with carry_in = 0 ----
    float A = 1.f, B = 0.f;
#pragma unroll
    for (int i = 0; i < SEG - 1; ++i) {
        float2 w = cs[i * LPR + t];
        B = w.y * B + w.x * v[i + 1];
        A = w.y * A;
    }
    {   // last step of segment consumes the boundary element
        float2 w = cs[(SEG - 1) * LPR + t];
        B = w.y * B + w.x * vnext;   // lane 31: garbage-but-finite, result unused
        A = w.y * A;
    }

    // ---- inclusive affine scan across the 32 lanes of this row ----
#pragma unroll
    for (int d = 1; d < LPR; d <<= 1) {
        float pa = __shfl_up(A, d, LPR);
        float pb = __shfl_up(B, d, LPR);
        if (t >= d) { B = A * pb + B; A = A * pa; }
    }
    // exclusive prefix -> carry entering this lane's segment
    float ea = __shfl_up(A, 1, LPR);
    float eb = __shfl_up(B, 1, LPR);
    if (t == 0) { ea = 1.f; eb = 0.f; }
    float carry = ea * v0row + eb;

    // provisional out[0] (result of step 0), needed by the wrap step 1023
    float2 w0 = cs[0];
    float out0_prov = w0.x * v0row - w0.y * v1row;

    // ---- phase 2: replay with true carry, write outputs into v[] ----
#pragma unroll
    for (int i = 0; i < SEG - 1; ++i) {
        float2 w = cs[i * LPR + t];
        float vn = v[i + 1];
        float o  = w.x * carry - w.y * vn;
        carry    = w.y * carry + w.x * vn;
        v[i] = o;
    }
    {   // last step; lane 31 executes the wrap step 1023 against out[0]
        float2 w  = cs[(SEG - 1) * LPR + t];
        float vn  = (t == LPR - 1) ? out0_prov : vnext;
        float o   = w.x * carry - w.y * vn;
        float nc  = w.y * carry + w.x * vn;
        v[SEG - 1] = o;
        float out0_final = __shfl(nc, LPR - 1, LPR);  // lane 31 -> all
        if (t == 0) v[0] = out0_final;
    }

    // ---- stage to wave-private LDS, then fully-coalesced float4 stores ----
    const int half = grp & 1;   // which of the wave's 2 rows
#pragma unroll
    for (int e = 0; e < SEG4; ++e) {
        int idx = half * 256 + t * SEG4 + e;
        stage[wave][idx + (idx >> 3)] =
            make_float4(v[4*e+0], v[4*e+1], v[4*e+2], v[4*e+3]);
    }
    // wave-private buffer: same-wave LDS RAW is ordered via lgkmcnt, no barrier.
    const int l = tid & 63;
    const int firstRow = blockIdx.x * ROWS_PER_BLOCK + wave * 2;
    float4* gout4 = reinterpret_cast<float4*>(out) + (size_t)firstRow * (DIM / 4);
    if (firstRow + 2 <= batch) {
#pragma unroll
        for (int m = 0; m < 8; ++m) {
            int idx = m * 64 + l;                 // 1KB contiguous per instruction
            gout4[idx] = stage[wave][idx + (idx >> 3)];
        }
    } else {
        for (int m = 0; m < 8; ++m) {
            int idx = m * 64 + l;
            int r = firstRow + (idx >> 8);
            if (r < batch) gout4[idx] = stage[wave][idx + (idx >> 3)];
        }
    }
}

extern "C" void kernel_launch(void* const* d_in, const int* in_sizes, int n_in,
                              void* d_out, int out_size, void* d_ws, size_t ws_size,
                              hipStream_t stream) {
    const float* x      = (const float*)d_in[0];
    const float* angles = (const float*)d_in[1];
    float* outp         = (float*)d_out;

    int batch = in_sizes[0] / DIM;                       // 65536
    int grid  = (batch + ROWS_PER_BLOCK - 1) / ROWS_PER_BLOCK;  // 8192
    qll_kernel<<<grid, 256, 0, stream>>>(x, angles, outp, batch);
}

// Round 3
// 90.699 us; speedup vs baseline: 3.5517x; 1.1929x over previous
//
#include <hip/hip_runtime.h>

#define DIM   1024
#define LPR   32            // lanes cooperating on one row
#define SEG   (DIM / LPR)   // 32 floats per lane
#define SEG4  (SEG / 4)     // 8 float4 per lane
#define ROWS_PER_BLOCK 8    // 256 threads / 32
#define WAVES_PER_BLOCK 4

typedef float f32x4 __attribute__((ext_vector_type(4)));

// Row recurrence (Givens sweep): carry = value of column i entering step i.
//   out[i]  = c_i*carry - s_i*v[i+1]
//   carry'  = s_i*carry + c_i*v[i+1]
// Affine in carry -> per-lane (A,B) + shfl scan parallelizes across 32 lanes.
//
// I/O plan: all global traffic is fully coalesced 1KB/instr. The wave's two
// contiguous rows (8KB) are staged into LDS via global_load_lds with an
// XOR-involution-permuted SOURCE (linear LDS dest), so the per-lane segment
// ds_read_b128 at the SAME xor-swizzled index is linear data AND spreads the
// 32 lanes across all banks (4-pass minimum = conflict-free).
__global__ __launch_bounds__(256, 4)
void qll_kernel(const float* __restrict__ x,
                const float* __restrict__ angles,
                float* __restrict__ out,
                int batch)
{
    // cos/sin table, bank-transposed: step j at [(j&31)*32 + (j>>5)] so the
    // phase-loop read cs[i*32+t] puts lane t in bank 2t%32 (2-way = free).
    __shared__ float2 cs[DIM];                      // 8 KB
    __shared__ f32x4  stage[WAVES_PER_BLOCK][512];  // 32 KB, wave-private row-pair

    for (int j = threadIdx.x; j < DIM; j += blockDim.x) {
        float a = angles[j];
        cs[(j & 31) * LPR + (j >> 5)] = make_float2(cosf(a), sinf(a));
    }
    __syncthreads();

    const int tid  = threadIdx.x;
    const int l    = tid & 63;        // lane in wave
    const int wave = tid >> 6;        // 0..3
    const int h    = (tid >> 5) & 1;  // which row of the wave's pair
    const int t    = tid & 31;        // segment index within row
    const int r0   = blockIdx.x * ROWS_PER_BLOCK + wave * 2;
    if (r0 + 2 > batch) return;       // wave-uniform; batch is even

    // XOR involution on the low-3 bits of the float4 index:
    //   p(idx) = idx ^ ((idx>>3)&7). Applied to the SOURCE lane offset here,
    //   and to the ds_read/ds_write index below. p(p(idx)) == idx.
    const int swz_l = l ^ ((l >> 3) & 7);

    // ---- stage the contiguous row pair (8 KB) into LDS, coalesced ----
    const f32x4* gin = reinterpret_cast<const f32x4*>(x) + (size_t)r0 * 256;
#pragma unroll
    for (int m = 0; m < 8; ++m) {
        __builtin_amdgcn_global_load_lds(
            (const __attribute__((address_space(1))) void*)(gin + m * 64 + swz_l),
            (__attribute__((address_space(3))) void*)(&stage[wave][m * 64]),
            16, 0, 0);
    }
    asm volatile("s_waitcnt vmcnt(0)" ::: "memory");
    __builtin_amdgcn_sched_barrier(0);

    // ---- read this lane's 32-float segment (bank-conflict-free b128s) ----
    float v[SEG];
#pragma unroll
    for (int e = 0; e < SEG4; ++e) {
        f32x4 q = stage[wave][h * 256 + t * 8 + (e ^ (t & 7))];
        v[4*e+0] = q.x; v[4*e+1] = q.y; v[4*e+2] = q.z; v[4*e+3] = q.w;
    }

    // boundary exchanges (capture BEFORE phase 2 overwrites v[])
    float v0row = __shfl(v[0], 0, LPR);        // row's v[0]
    float v1row = __shfl(v[1], 0, LPR);        // row's v[1]
    float vnext = __shfl_down(v[0], 1, LPR);   // next lane's first elem (t=31: own, unused)

    // ---- phase 1: per-lane affine (A,B) with carry_in = 0 ----
    float A = 1.f, B = 0.f;
#pragma unroll
    for (int i = 0; i < SEG - 1; ++i) {
        float2 w = cs[i * LPR + t];
        B = w.y * B + w.x * v[i + 1];
        A = w.y * A;
    }
    {   // last step of segment consumes the boundary element
        float2 w = cs[(SEG - 1) * LPR + t];
        B = w.y * B + w.x * vnext;   // lane 31: finite garbage, result unused
        A = w.y * A;
    }

    // ---- inclusive affine scan across the 32 lanes of this row ----
#pragma unroll
    for (int d = 1; d < LPR; d <<= 1) {
        float pa = __shfl_up(A, d, LPR);
        float pb = __shfl_up(B, d, LPR);
        if (t >= d) { B = A * pb + B; A = A * pa; }
    }
    // exclusive prefix -> carry entering this lane's segment
    float ea = __shfl_up(A, 1, LPR);
    float eb = __shfl_up(B, 1, LPR);
    if (t == 0) { ea = 1.f; eb = 0.f; }
    float carry = ea * v0row + eb;

    // provisional out[0] (result of step 0), needed by the wrap step 1023
    float2 w0 = cs[0];
    float out0_prov = w0.x * v0row - w0.y * v1row;

    // ---- phase 2: replay with true carry, outputs into v[] ----
#pragma unroll
    for (int i = 0; i < SEG - 1; ++i) {
        float2 w = cs[i * LPR + t];
        float vn = v[i + 1];
        float o  = w.x * carry - w.y * vn;
        carry    = w.y * carry + w.x * vn;
        v[i] = o;
    }
    {   // last step; lane 31 executes the wrap step 1023 against out[0]
        float2 w  = cs[(SEG - 1) * LPR + t];
        float vn  = (t == LPR - 1) ? out0_prov : vnext;
        float o   = w.x * carry - w.y * vn;
        float nc  = w.y * carry + w.x * vn;
        v[SEG - 1] = o;
        float out0_final = __shfl(nc, LPR - 1, LPR);  // lane 31 -> all
        if (t == 0) v[0] = out0_final;
    }

    // ---- out-stage into the same buffer (in-order DS pipe: same-wave WAR
    //      after the earlier reads is safe), then coalesced nt stores ----
#pragma unroll
    for (int e = 0; e < SEG4; ++e) {
        f32x4 q = { v[4*e+0], v[4*e+1], v[4*e+2], v[4*e+3] };
        stage[wave][h * 256 + t * 8 + (e ^ (t & 7))] = q;
    }
    f32x4* gout = reinterpret_cast<f32x4*>(out) + (size_t)r0 * 256;
#pragma unroll
    for (int m = 0; m < 8; ++m) {
        f32x4 q = stage[wave][m * 64 + swz_l];
        __builtin_nontemporal_store(q, gout + m * 64 + l);
    }
}

extern "C" void kernel_launch(void* const* d_in, const int* in_sizes, int n_in,
                              void* d_out, int out_size, void* d_ws, size_t ws_size,
                              hipStream_t stream) {
    const float* x      = (const float*)d_in[0];
    const float* angles = (const float*)d_in[1];
    float* outp         = (float*)d_out;

    int batch = in_sizes[0] / DIM;                              // 65536
    int grid  = (batch + ROWS_PER_BLOCK - 1) / ROWS_PER_BLOCK;  // 8192
    qll_kernel<<<grid, 256, 0, stream>>>(x, angles, outp, batch);
}